// Round 1
// baseline (215.510 us; speedup 1.0000x reference)
//
#include <hip/hip_runtime.h>
#include <hip/hip_bf16.h>
#include <math.h>

#define Bsz 2048
#define Lsz 1024
#define Hsz 64
#define Vsz 64
#define Tsteps 1023   // keys are h[:, :-1, :]
#define WPB 8         // waves (batches) per block

// ws layout (float offsets)
#define OFF_TABLE 0        // hh table        64x64
#define OFF_G     4096     // Gram            64x64
#define OFF_GC    8192     // c_v * G[v][:]   64x64
#define OFF_P     12288    // table @ (read_w @ out_w)  64x64
#define OFF_GV    16384    // g per token     64
#define OFF_BC    16448    // read_b@out_w + out_b      64
// total 16512 floats = ~64.5 KB of d_ws

__global__ __launch_bounds__(1024) void prep_kernel(
    const float* __restrict__ embed_W, const float* __restrict__ ff_w1, const float* __restrict__ ff_b1,
    const float* __restrict__ ff_w2, const float* __restrict__ ff_b2, const float* __restrict__ ln_g,
    const float* __restrict__ ln_b, const float* __restrict__ gate_w1, const float* __restrict__ gate_b1,
    const float* __restrict__ gate_w2, const float* __restrict__ gate_b2, const float* __restrict__ read_w,
    const float* __restrict__ read_b, const float* __restrict__ out_w, const float* __restrict__ out_b,
    float* __restrict__ ws)
{
    __shared__ float shE[4096];   // embeddings 64x64
    __shared__ float shZ[8192];   // relu(E@W1+b1) 64x128
    __shared__ float shH[4096];   // x then hh 64x64
    __shared__ float shWc[4096];  // read_w @ out_w
    __shared__ float shc[64];
    const int tid = threadIdx.x;

    for (int i = tid; i < 4096; i += 1024) shE[i] = embed_W[i];
    __syncthreads();

    // z1 = relu(E @ ff_w1 + b1): 64 x 128
    for (int idx = tid; idx < 8192; idx += 1024) {
        int v = idx >> 7, j = idx & 127;
        float a = ff_b1[j];
        const float* e = &shE[v << 6];
        #pragma unroll 8
        for (int i = 0; i < 64; ++i) a = fmaf(e[i], ff_w1[i * 128 + j], a);
        shZ[idx] = fmaxf(a, 0.0f);
    }
    __syncthreads();

    // x = E + z1 @ ff_w2 + b2
    for (int idx = tid; idx < 4096; idx += 1024) {
        int v = idx >> 6, i = idx & 63;
        float a = ff_b2[i];
        const float* z = &shZ[v << 7];
        #pragma unroll 8
        for (int j = 0; j < 128; ++j) a = fmaf(z[j], ff_w2[j * 64 + i], a);
        shH[idx] = a + shE[idx];
    }
    __syncthreads();

    // LayerNorm + gate + c per token (64 threads, one per token)
    if (tid < 64) {
        const int v = tid;
        float* x = &shH[v << 6];
        float mu = 0.f;
        for (int i = 0; i < 64; ++i) mu += x[i];
        mu *= (1.0f / 64.0f);
        float var = 0.f;
        for (int i = 0; i < 64; ++i) { float dd = x[i] - mu; var = fmaf(dd, dd, var); }
        var *= (1.0f / 64.0f);
        const float rstd = rsqrtf(var + 1e-5f);
        float denom = 0.f;
        for (int i = 0; i < 64; ++i) {
            float hv = fmaf((x[i] - mu) * rstd, ln_g[i], ln_b[i]);
            x[i] = hv;
            denom = fmaf(hv, hv, denom);
        }
        denom += 1e-6f;
        float a2 = gate_b2[0];
        for (int m = 0; m < 16; ++m) {
            float u = gate_b1[m];
            for (int i = 0; i < 64; ++i) u = fmaf(x[i], gate_w1[i * 16 + m], u);
            a2 = fmaf(fmaxf(u, 0.0f), gate_w2[m], a2);
        }
        const float gg = 1.0f / (1.0f + expf(-a2));
        const float cc = gg / denom;
        ws[OFF_GV + v] = gg;
        shc[v] = cc;
    }
    __syncthreads();

    // table, Gram, scaled Gram
    for (int idx = tid; idx < 4096; idx += 1024) {
        ws[OFF_TABLE + idx] = shH[idx];
        int v = idx >> 6, w = idx & 63;
        float a = 0.f;
        const float* hv = &shH[v << 6];
        const float* hw = &shH[w << 6];
        #pragma unroll 8
        for (int j = 0; j < 64; ++j) a = fmaf(hv[j], hw[j], a);
        ws[OFF_G + idx]  = a;
        ws[OFF_GC + idx] = shc[v] * a;
    }
    // Wc = read_w @ out_w
    for (int idx = tid; idx < 4096; idx += 1024) {
        int j = idx >> 6, i = idx & 63;
        float a = 0.f;
        #pragma unroll 8
        for (int m = 0; m < 64; ++m) a = fmaf(read_w[j * 64 + m], out_w[m * 64 + i], a);
        shWc[idx] = a;
    }
    __syncthreads();
    // bc = read_b @ out_w + out_b
    if (tid < 64) {
        const int i = tid;
        float a = out_b[i];
        for (int j = 0; j < 64; ++j) a = fmaf(read_b[j], out_w[j * 64 + i], a);
        ws[OFF_BC + i] = a;
    }
    // P = table @ Wc
    for (int idx = tid; idx < 4096; idx += 1024) {
        int v = idx >> 6, i = idx & 63;
        float a = 0.f;
        const float* hv = &shH[v << 6];
        #pragma unroll 8
        for (int j = 0; j < 64; ++j) a = fmaf(hv[j], shWc[j * 64 + i], a);
        ws[OFF_P + idx] = a;
    }
}

__global__ __launch_bounds__(WPB * 64) void scan_kernel(const int* __restrict__ seq,
                                                        const float* __restrict__ ws,
                                                        float* __restrict__ out)
{
    __shared__ float ldsGc[4096];
    __shared__ float ldsP[4096];
    __shared__ int   toks[WPB][Lsz];
    __shared__ float sbuf[WPB][64];
    __shared__ float lds_g[64];
    __shared__ float lds_bc[64];

    const int tid  = threadIdx.x;
    const int wave = tid >> 6;
    const int lane = tid & 63;

    for (int i = tid; i < 4096; i += WPB * 64) {
        ldsGc[i] = ws[OFF_GC + i];
        ldsP[i]  = ws[OFF_P + i];
    }
    if (tid < 64) {
        lds_g[tid]  = ws[OFF_GV + tid];
        lds_bc[tid] = ws[OFF_BC + tid];
    }
    const int b = blockIdx.x * WPB + wave;
    const int* row = seq + (size_t)b * Lsz;
    for (int i = lane; i < Lsz; i += 64) toks[wave][i] = row[i];
    __syncthreads();

    // init: w = q = table[tokL]  =>  D_v = e_v . q = G[tokL][v]
    const int tokL = toks[wave][Lsz - 1];
    float D = ws[OFF_G + (tokL << 6) + lane];
    const float vg = lds_g[lane];
    float s_acc = 0.0f;

    // backward scan: d = k_t . w ; s[tok] += g*d ; w -= c*d*k_t  (in Gram basis)
    #pragma unroll 4
    for (int t = Tsteps - 1; t >= 0; --t) {
        const int tok = toks[wave][t];
        const float Gc = ldsGc[(tok << 6) + lane];                 // c_tok * G[tok][lane], prefetchable
        const float d = __int_as_float(
            __builtin_amdgcn_readlane(__float_as_int(D), tok));    // critical chain
        s_acc = fmaf((lane == tok) ? vg : 0.0f, d, s_acc);         // off-chain
        D = fmaf(-d, Gc, D);                                       // critical chain
    }

    sbuf[wave][lane] = s_acc;
    __syncthreads();

    // logits = s @ P + bc   (ctx, read head, out head all folded into P/bc)
    float acc = lds_bc[lane];
    #pragma unroll
    for (int v = 0; v < 64; ++v)
        acc = fmaf(sbuf[wave][v], ldsP[(v << 6) + lane], acc);
    out[(size_t)b * 64 + lane] = acc;
}

extern "C" void kernel_launch(void* const* d_in, const int* in_sizes, int n_in,
                              void* d_out, int out_size, void* d_ws, size_t ws_size,
                              hipStream_t stream) {
    const int*   seq     = (const int*)  d_in[0];
    const float* embed_W = (const float*)d_in[1];
    const float* ff_w1   = (const float*)d_in[2];
    const float* ff_b1   = (const float*)d_in[3];
    const float* ff_w2   = (const float*)d_in[4];
    const float* ff_b2   = (const float*)d_in[5];
    const float* ln_g    = (const float*)d_in[6];
    const float* ln_b    = (const float*)d_in[7];
    const float* gate_w1 = (const float*)d_in[8];
    const float* gate_b1 = (const float*)d_in[9];
    const float* gate_w2 = (const float*)d_in[10];
    const float* gate_b2 = (const float*)d_in[11];
    const float* read_w  = (const float*)d_in[12];
    const float* read_b  = (const float*)d_in[13];
    const float* out_w   = (const float*)d_in[14];
    const float* out_b   = (const float*)d_in[15];
    float* ws  = (float*)d_ws;
    float* out = (float*)d_out;

    hipLaunchKernelGGL(prep_kernel, dim3(1), dim3(1024), 0, stream,
                       embed_W, ff_w1, ff_b1, ff_w2, ff_b2, ln_g, ln_b,
                       gate_w1, gate_b1, gate_w2, gate_b2, read_w, read_b,
                       out_w, out_b, ws);
    hipLaunchKernelGGL(scan_kernel, dim3(Bsz / WPB), dim3(WPB * 64), 0, stream,
                       seq, ws, out);
}

// Round 2
// 137.258 us; speedup vs baseline: 1.5701x; 1.5701x over previous
//
#include <hip/hip_runtime.h>
#include <hip/hip_bf16.h>
#include <math.h>

#define Bsz 2048
#define Lsz 1024
#define Hsz 64
#define Vsz 64
#define SW  8   // waves (batches) per scan block

// ws layout (float offsets)
#define OFF_TABLE 0        // h table            64x64
#define OFF_G     4096     // Gram               64x64
#define OFF_GC    8192     // c_v * G[v][:]      64x64
#define OFF_P     12288    // table @ Wc         64x64
#define OFF_WC    16384    // read_w @ out_w     64x64
#define OFF_GV    20480    // g per token        64
#define OFF_C     20544    // c per token        64
#define OFF_BC    20608    // read_b@out_w+out_b 64
// total 20672 floats ~= 83 KB of d_ws

// ---------------- prep1: per-token h/g/c (blocks 0..63), Wc rows (64..127), bc (128)
__global__ __launch_bounds__(128) void prep1_kernel(
    const float* __restrict__ embed_W, const float* __restrict__ ff_w1, const float* __restrict__ ff_b1,
    const float* __restrict__ ff_w2, const float* __restrict__ ff_b2, const float* __restrict__ ln_g,
    const float* __restrict__ ln_b, const float* __restrict__ gate_w1, const float* __restrict__ gate_b1,
    const float* __restrict__ gate_w2, const float* __restrict__ gate_b2, const float* __restrict__ read_w,
    const float* __restrict__ read_b, const float* __restrict__ out_w, const float* __restrict__ out_b,
    float* __restrict__ ws)
{
    const int tid = threadIdx.x;
    const int blk = blockIdx.x;
    if (blk < 64) {
        const int v = blk;
        __shared__ float z[128];
        __shared__ float hsh[64];
        const float* Ev = embed_W + (v << 6);
        // z = relu(E[v] @ ff_w1 + b1), 128 cols, one per thread
        float a = ff_b1[tid];
        #pragma unroll
        for (int i = 0; i < 64; ++i) a = fmaf(Ev[i], ff_w1[i * 128 + tid], a);
        z[tid] = fmaxf(a, 0.0f);
        __syncthreads();
        if (tid < 64) {   // wave 0 only
            float x = Ev[tid] + ff_b2[tid];
            #pragma unroll
            for (int j = 0; j < 128; ++j) x = fmaf(z[j], ff_w2[j * 64 + tid], x);
            // layernorm via wave64 butterfly reductions
            float mu = x;
            #pragma unroll
            for (int off = 32; off > 0; off >>= 1) mu += __shfl_xor(mu, off);
            mu *= (1.0f / 64.0f);
            const float dd = x - mu;
            float var = dd * dd;
            #pragma unroll
            for (int off = 32; off > 0; off >>= 1) var += __shfl_xor(var, off);
            var *= (1.0f / 64.0f);
            const float rstd = rsqrtf(var + 1e-5f);
            const float hv = fmaf(dd * rstd, ln_g[tid], ln_b[tid]);
            ws[OFF_TABLE + (v << 6) + tid] = hv;
            hsh[tid] = hv;
            float dn = hv * hv;
            #pragma unroll
            for (int off = 32; off > 0; off >>= 1) dn += __shfl_xor(dn, off);
            dn += 1e-6f;   // denom (all lanes)
            // gate: lanes 0..15 compute u_m, reduce within low 16 lanes
            float a2 = 0.0f;
            if (tid < 16) {
                float um = gate_b1[tid];
                #pragma unroll
                for (int i = 0; i < 64; ++i) um = fmaf(hsh[i], gate_w1[i * 16 + tid], um);
                a2 = fmaxf(um, 0.0f) * gate_w2[tid];
            }
            #pragma unroll
            for (int off = 8; off > 0; off >>= 1) a2 += __shfl_xor(a2, off);
            if (tid == 0) {
                a2 += gate_b2[0];
                const float g = 1.0f / (1.0f + expf(-a2));
                ws[OFF_GV + v] = g;
                ws[OFF_C + v]  = g / dn;
            }
        }
    } else if (blk < 128) {
        const int j = blk - 64;
        if (tid < 64) {
            float a = 0.0f;
            #pragma unroll
            for (int m = 0; m < 64; ++m) a = fmaf(read_w[(j << 6) + m], out_w[(m << 6) + tid], a);
            ws[OFF_WC + (j << 6) + tid] = a;
        }
    } else {
        if (tid < 64) {
            float a = out_b[tid];
            #pragma unroll
            for (int jj = 0; jj < 64; ++jj) a = fmaf(read_b[jj], out_w[(jj << 6) + tid], a);
            ws[OFF_BC + tid] = a;
        }
    }
}

// ---------------- prep2: Gram rows (blocks 0..63), P rows (64..127)
__global__ __launch_bounds__(64) void prep2_kernel(float* __restrict__ ws)
{
    const int tid = threadIdx.x;
    const int blk = blockIdx.x;
    if (blk < 64) {
        const int v = blk;
        __shared__ float tT[65 * 64];   // tT[j*65+w] = table[w][j] (padded: conflict-free)
        for (int idx = tid; idx < 4096; idx += 64) {
            const int w = idx >> 6, j = idx & 63;
            tT[j * 65 + w] = ws[OFF_TABLE + idx];
        }
        __syncthreads();
        const float cv = ws[OFF_C + v];
        float a = 0.0f;
        #pragma unroll
        for (int j = 0; j < 64; ++j) a = fmaf(tT[j * 65 + v], tT[j * 65 + tid], a);
        ws[OFF_G  + (v << 6) + tid] = a;
        ws[OFF_GC + (v << 6) + tid] = cv * a;
    } else {
        const int v = blk - 64;
        float a = 0.0f;
        #pragma unroll
        for (int j = 0; j < 64; ++j)
            a = fmaf(ws[OFF_TABLE + (v << 6) + j], ws[OFF_WC + (j << 6) + tid], a);
        ws[OFF_P + (v << 6) + tid] = a;
    }
}

// ---------------- scan: one wave per batch, software-pipelined 16-step blocks
__global__ __launch_bounds__(SW * 64) void scan_kernel(const int* __restrict__ seq,
                                                       const float* __restrict__ ws,
                                                       float* __restrict__ out)
{
    __shared__ float ldsGc[65 * 64];   // rows 0..63 real, row 64 zeros (dummy token)
    __shared__ float ldsP[4096];
    __shared__ int   toks[SW][1024];
    __shared__ float sbuf[SW][64];
    __shared__ float ldsg[64];
    __shared__ float ldsbc[64];

    const int tid  = threadIdx.x;
    const int wave = tid >> 6;
    const int lane = tid & 63;

    for (int i = tid; i < 4096; i += SW * 64) {
        ldsGc[i] = ws[OFF_GC + i];
        ldsP[i]  = ws[OFF_P + i];
    }
    if (tid < 64) {
        ldsGc[4096 + tid] = 0.0f;
        ldsg[tid]  = ws[OFF_GV + tid];
        ldsbc[tid] = ws[OFF_BC + tid];
    }
    const int b = blockIdx.x * SW + wave;
    const int* row = seq + (size_t)b * Lsz;
    {
        int4* dst = (int4*)toks[wave];
        const int4* src = (const int4*)row;
        for (int i = lane; i < 256; i += 64) dst[i] = src[i];
    }
    __syncthreads();

    const int tokL = toks[wave][1023];   // query token
    toks[wave][1023] = 64;               // pad step t=1023 -> dummy token (Gc row = 0)
    float D = ws[OFF_G + (tokL << 6) + lane];   // D_v = e_v . q
    float u = 0.0f;

    int   tkA[16], tkB[16];
    float gcA[16], gcB[16];

    // prologue: toks for block A0 (steps 1023..1008), then its Gc; toks for B0
    int tokvA = toks[wave][1008 + lane];
    #pragma unroll
    for (int k = 0; k < 16; ++k) {
        tkA[k] = __builtin_amdgcn_readlane(tokvA, 15 - k) & 127;
        gcA[k] = ldsGc[(tkA[k] << 6) + lane];
    }
    int tokvB = toks[wave][992 + lane];

    for (int t0 = 1023; t0 > 0; t0 -= 32) {
        // Gc prefetch for B block (steps t0-16..t0-31)
        #pragma unroll
        for (int k = 0; k < 16; ++k) {
            tkB[k] = __builtin_amdgcn_readlane(tokvB, 15 - k) & 127;
            gcB[k] = ldsGc[(tkB[k] << 6) + lane];
        }
        // toks prefetch for next A block
        {
            const int base = t0 - 47;
            tokvA = toks[wave][(base < 0 ? 0 : base) + lane];
        }
        // compute A block (steps t0..t0-15, descending)
        #pragma unroll
        for (int k = 0; k < 16; ++k) {
            const int tok = tkA[k];
            const float d = __int_as_float(
                __builtin_amdgcn_readlane(__float_as_int(D), tok));
            u += (lane == tok) ? d : 0.0f;
            D = fmaf(-d, gcA[k], D);
        }
        // Gc prefetch for next A block (garbage-safe past the end: tok&127 keeps it in LDS)
        #pragma unroll
        for (int k = 0; k < 16; ++k) {
            tkA[k] = __builtin_amdgcn_readlane(tokvA, 15 - k) & 127;
            gcA[k] = ldsGc[(tkA[k] << 6) + lane];
        }
        // toks prefetch for next B block
        {
            const int base = t0 - 63;
            tokvB = toks[wave][(base < 0 ? 0 : base) + lane];
        }
        // compute B block (steps t0-16..t0-31)
        #pragma unroll
        for (int k = 0; k < 16; ++k) {
            const int tok = tkB[k];
            const float d = __int_as_float(
                __builtin_amdgcn_readlane(__float_as_int(D), tok));
            u += (lane == tok) ? d : 0.0f;
            D = fmaf(-d, gcB[k], D);
        }
    }

    // epilogue: s = g * u ; logits = s @ P + bc
    sbuf[wave][lane] = ldsg[lane] * u;
    float acc = ldsbc[lane];
    #pragma unroll 8
    for (int v = 0; v < 64; ++v)
        acc = fmaf(sbuf[wave][v], ldsP[(v << 6) + lane], acc);
    out[(size_t)b * 64 + lane] = acc;
}

extern "C" void kernel_launch(void* const* d_in, const int* in_sizes, int n_in,
                              void* d_out, int out_size, void* d_ws, size_t ws_size,
                              hipStream_t stream) {
    const int*   seq     = (const int*)  d_in[0];
    const float* embed_W = (const float*)d_in[1];
    const float* ff_w1   = (const float*)d_in[2];
    const float* ff_b1   = (const float*)d_in[3];
    const float* ff_w2   = (const float*)d_in[4];
    const float* ff_b2   = (const float*)d_in[5];
    const float* ln_g    = (const float*)d_in[6];
    const float* ln_b    = (const float*)d_in[7];
    const float* gate_w1 = (const float*)d_in[8];
    const float* gate_b1 = (const float*)d_in[9];
    const float* gate_w2 = (const float*)d_in[10];
    const float* gate_b2 = (const float*)d_in[11];
    const float* read_w  = (const float*)d_in[12];
    const float* read_b  = (const float*)d_in[13];
    const float* out_w   = (const float*)d_in[14];
    const float* out_b   = (const float*)d_in[15];
    float* ws  = (float*)d_ws;
    float* out = (float*)d_out;

    hipLaunchKernelGGL(prep1_kernel, dim3(129), dim3(128), 0, stream,
                       embed_W, ff_w1, ff_b1, ff_w2, ff_b2, ln_g, ln_b,
                       gate_w1, gate_b1, gate_w2, gate_b2, read_w, read_b,
                       out_w, out_b, ws);
    hipLaunchKernelGGL(prep2_kernel, dim3(128), dim3(64), 0, stream, ws);
    hipLaunchKernelGGL(scan_kernel, dim3(Bsz / SW), dim3(SW * 64), 0, stream,
                       seq, ws, out);
}